// Round 7
// baseline (1250.999 us; speedup 1.0000x reference)
//
#include <hip/hip_runtime.h>
#include <stdint.h>

// SequentialMLP (grouped MoE LLaMA-MLP), MI355X gfx950.
// E=64 experts x C=512 tokens, H=F=1024, f32 in/out, bf16 MFMA compute.
// R7: back to 16x16x32 MFMA (R6's 32x32 caused 4-way LDS conflicts, 3x
//     SQ_LDS_BANK_CONFLICT). Keep R6's vectorized B gather + reg transpose.
//     NEW: A-fragments loaded DIRECTLY from global to VGPR (coalesced 16B/lane,
//     L2-served via XCD-grouped blocks) -> A's LDS reads+writes eliminated,
//     LDS = B-only double buffer. 2-deep A-frag register pipeline with named
//     static buffers (rule #20). One __syncthreads per K-tile.

#define NUM_E 64
#define DIM_H 1024
#define DIM_F 1024
#define CAP   512
#define NTOK  32768

typedef short short8 __attribute__((ext_vector_type(8)));
typedef float f32x4 __attribute__((ext_vector_type(4)));

__device__ __forceinline__ uint32_t cvtpk(float lo, float hi) {
  uint32_t r;
  asm("v_cvt_pk_bf16_f32 %0, %1, %2" : "=v"(r) : "v"(lo), "v"(hi));
  return r;
}
__device__ __forceinline__ unsigned short f2bf(float a) {
  uint32_t ua = __builtin_bit_cast(uint32_t, a);
  ua += 0x7FFFu + ((ua >> 16) & 1u);
  return (unsigned short)(ua >> 16);
}

// ---------------- Kernel 0: x f32 -> bf16 ----------------
__global__ __launch_bounds__(256) void cvt_kernel(const float* __restrict__ x,
                                                  unsigned short* __restrict__ xbf) {
  size_t i = ((size_t)blockIdx.x * 256 + threadIdx.x) * 8;
  f32x4 a = *reinterpret_cast<const f32x4*>(x + i);
  f32x4 b = *reinterpret_cast<const f32x4*>(x + i + 4);
  int4 o = make_int4((int)cvtpk(a[0], a[1]), (int)cvtpk(a[2], a[3]),
                     (int)cvtpk(b[0], b[1]), (int)cvtpk(b[2], b[3]));
  *reinterpret_cast<int4*>(xbf + i) = o;
}

// ------ Kernel 1: h = silu(x Wg)*(x Wu).  256m x (128g+128u), BK=64 ------
// 512 thr / 8 waves (4m x 2n), wave tile 64x64 per matrix, 16x16x32 MFMA.
// Grid 64e x 2mb x 8nb = 1024. LDS 64KB: B dbuf 2 x {Bg^T 16KB, Bu^T 16KB}.
__global__ __launch_bounds__(512, 2) void gateup_kernel_v5(
    const unsigned short* __restrict__ xbf, const float* __restrict__ wg,
    const float* __restrict__ wu, unsigned short* __restrict__ hout)
{
  __shared__ unsigned char smem[65536];
  const int t = threadIdx.x;
  int bid = blockIdx.x;
  bid = (bid & 7) * 128 + (bid >> 3);          // XCD-bijective (1024 = 8*128)
  const int e = bid >> 4, rr = bid & 15, mb = rr >> 3, nb = rr & 7;
  const int row0 = e * CAP + mb * 256;
  const int col0 = nb * 128;
  const unsigned short* Ag = xbf + (size_t)row0 * DIM_H;
  const float* Bgg = wg + (size_t)e * (DIM_H * DIM_F) + col0;
  const float* Bug = wu + (size_t)e * (DIM_H * DIM_F) + col0;

  const int lane = t & 63, wid = t >> 6;
  const int wm = wid >> 1, wn = wid & 1;       // wave tile 64m x 64n (per matrix)

  f32x4 accg[4][4], accu[4][4];
  #pragma unroll
  for (int i = 0; i < 4; i++)
    #pragma unroll
    for (int j = 0; j < 4; j++) {
      accg[i][j] = f32x4{0.f, 0.f, 0.f, 0.f};
      accu[i][j] = f32x4{0.f, 0.f, 0.f, 0.f};
    }

  // B staging: thread covers 4k x 4n f32 per matrix (dwordx4 x4, reg transpose)
  const int kg = t & 15, ng = t >> 4;
  f32x4 vg[4], vu[4];

  auto loadB = [&](int k0) {
    #pragma unroll
    for (int i = 0; i < 4; i++) {
      size_t off = (size_t)(k0 + kg * 4 + i) * DIM_F + ng * 4;
      vg[i] = *reinterpret_cast<const f32x4*>(Bgg + off);
      vu[i] = *reinterpret_cast<const f32x4*>(Bug + off);
    }
  };
  auto writeB = [&](int b) {
    const int Bb = b * 32768;
    #pragma unroll
    for (int j = 0; j < 4; j++) {
      int n = ng * 4 + j;
      int off = Bb + n * 128 + ((kg * 8) ^ ((n & 7) << 4));
      *reinterpret_cast<uint2*>(&smem[off]) =
          make_uint2(cvtpk(vg[0][j], vg[1][j]), cvtpk(vg[2][j], vg[3][j]));
      *reinterpret_cast<uint2*>(&smem[off + 16384]) =
          make_uint2(cvtpk(vu[0][j], vu[1][j]), cvtpk(vu[2][j], vu[3][j]));
    }
  };
  // A-fragments direct from global: frag[mi*2+kk], row = wm*64+mi*16+(lane&15),
  // 8 contiguous bf16 at k = k0 + kk*32 + (lane>>4)*8. Coalesced 16B/lane.
  auto ldA = [&](int k0, short8 (&dst)[8]) {
    #pragma unroll
    for (int mi = 0; mi < 4; mi++) {
      int row = wm * 64 + mi * 16 + (lane & 15);
      const unsigned short* base = Ag + (size_t)row * DIM_H + k0 + ((lane >> 4) & 3) * 8;
      #pragma unroll
      for (int kk = 0; kk < 2; kk++)
        dst[mi * 2 + kk] = *reinterpret_cast<const short8*>(base + kk * 32);
    }
  };
  auto compute = [&](int b, const short8 (&a)[8]) {
    const int Bb = b * 32768;
    __builtin_amdgcn_s_setprio(1);
    #pragma unroll
    for (int kk = 0; kk < 2; kk++) {
      short8 bgf[4], buf_[4];
      #pragma unroll
      for (int ni = 0; ni < 4; ni++) {
        int n = wn * 64 + ni * 16 + (lane & 15);
        int off = Bb + n * 128 + ((kk * 64 + (lane >> 4) * 16) ^ ((n & 7) << 4));
        bgf[ni]  = *reinterpret_cast<const short8*>(&smem[off]);
        buf_[ni] = *reinterpret_cast<const short8*>(&smem[off + 16384]);
      }
      #pragma unroll
      for (int mi = 0; mi < 4; mi++)
        #pragma unroll
        for (int ni = 0; ni < 4; ni++) {
          accg[mi][ni] = __builtin_amdgcn_mfma_f32_16x16x32_bf16(a[mi*2+kk], bgf[ni],  accg[mi][ni], 0, 0, 0);
          accu[mi][ni] = __builtin_amdgcn_mfma_f32_16x16x32_bf16(a[mi*2+kk], buf_[ni], accu[mi][ni], 0, 0, 0);
        }
    }
    __builtin_amdgcn_s_setprio(0);
  };

  short8 a0[8], a1[8];
  const int NT = DIM_H / 64;   // 16
  loadB(0);
  ldA(0, a0);
  writeB(0);
  __syncthreads();
  #pragma unroll 1
  for (int it = 0; it < NT / 2; it++) {
    const int kt1 = it * 2 + 1;
    // phase A: compute kt0 (buf0, a0); prefetch kt1 (buf1, a1)
    loadB(kt1 * 64);
    ldA(kt1 * 64, a1);
    compute(0, a0);
    writeB(1);
    __syncthreads();
    // phase B: compute kt1 (buf1, a1); prefetch kt1+1 (buf0, a0)
    if (kt1 + 1 < NT) {
      loadB((kt1 + 1) * 64);
      ldA((kt1 + 1) * 64, a0);
    }
    compute(1, a1);
    if (kt1 + 1 < NT) writeB(0);
    __syncthreads();
  }

  // epilogue: silu(g)*u -> bf16. C/D: col=lane&15, row=(lane>>4)*4+j.
  #pragma unroll
  for (int mi = 0; mi < 4; mi++)
    #pragma unroll
    for (int ni = 0; ni < 4; ni++) {
      int col = col0 + wn * 64 + ni * 16 + (lane & 15);
      int rbase = row0 + wm * 64 + mi * 16 + (lane >> 4) * 4;
      #pragma unroll
      for (int j = 0; j < 4; j++) {
        float g = accg[mi][ni][j], u = accu[mi][ni][j];
        float hv = (g / (1.f + __expf(-g))) * u;
        hout[(size_t)(rbase + j) * DIM_F + col] = f2bf(hv);
      }
    }
}

// ---------------- Kernel 2: out = h Wd, f32 out.  256m x 128n ----------------
// 512 thr / 8 waves (4m x 2n), wave 64x64, 16x16x32 MFMA. Grid 1024.
// LDS 32KB: Bd^T dbuf 2 x 16KB. A-fragments direct from global (h is bf16).
__global__ __launch_bounds__(512, 2) void down_kernel_v5(
    const unsigned short* __restrict__ hin, const float* __restrict__ wd,
    float* __restrict__ out)
{
  __shared__ unsigned char smem[32768];
  const int t = threadIdx.x;
  int bid = blockIdx.x;
  bid = (bid & 7) * 128 + (bid >> 3);          // XCD-bijective (1024 = 8*128)
  const int e = bid >> 4, rr = bid & 15, mb = rr >> 3, nb = rr & 7;
  const int row0 = e * CAP + mb * 256;
  const int col0 = nb * 128;
  const unsigned short* Ag = hin + (size_t)row0 * DIM_F;
  const float* Bdg = wd + (size_t)e * (DIM_F * DIM_H) + col0;

  const int lane = t & 63, wid = t >> 6;
  const int wm = wid >> 1, wn = wid & 1;

  f32x4 acc[4][4];
  #pragma unroll
  for (int i = 0; i < 4; i++)
    #pragma unroll
    for (int j = 0; j < 4; j++) acc[i][j] = f32x4{0.f, 0.f, 0.f, 0.f};

  const int kg = t & 15, ng = t >> 4;
  f32x4 vb[4];

  auto loadB = [&](int k0) {
    #pragma unroll
    for (int i = 0; i < 4; i++)
      vb[i] = *reinterpret_cast<const f32x4*>(Bdg + (size_t)(k0 + kg * 4 + i) * DIM_H + ng * 4);
  };
  auto writeB = [&](int b) {
    const int Bb = b * 16384;
    #pragma unroll
    for (int j = 0; j < 4; j++) {
      int n = ng * 4 + j;
      int off = Bb + n * 128 + ((kg * 8) ^ ((n & 7) << 4));
      *reinterpret_cast<uint2*>(&smem[off]) =
          make_uint2(cvtpk(vb[0][j], vb[1][j]), cvtpk(vb[2][j], vb[3][j]));
    }
  };
  auto ldA = [&](int k0, short8 (&dst)[8]) {
    #pragma unroll
    for (int mi = 0; mi < 4; mi++) {
      int row = wm * 64 + mi * 16 + (lane & 15);
      const unsigned short* base = Ag + (size_t)row * DIM_F + k0 + ((lane >> 4) & 3) * 8;
      #pragma unroll
      for (int kk = 0; kk < 2; kk++)
        dst[mi * 2 + kk] = *reinterpret_cast<const short8*>(base + kk * 32);
    }
  };
  auto compute = [&](int b, const short8 (&a)[8]) {
    const int Bb = b * 16384;
    __builtin_amdgcn_s_setprio(1);
    #pragma unroll
    for (int kk = 0; kk < 2; kk++) {
      short8 bf[4];
      #pragma unroll
      for (int ni = 0; ni < 4; ni++) {
        int n = wn * 64 + ni * 16 + (lane & 15);
        bf[ni] = *reinterpret_cast<const short8*>(
            &smem[Bb + n * 128 + ((kk * 64 + (lane >> 4) * 16) ^ ((n & 7) << 4))]);
      }
      #pragma unroll
      for (int mi = 0; mi < 4; mi++)
        #pragma unroll
        for (int ni = 0; ni < 4; ni++)
          acc[mi][ni] = __builtin_amdgcn_mfma_f32_16x16x32_bf16(a[mi*2+kk], bf[ni], acc[mi][ni], 0, 0, 0);
    }
    __builtin_amdgcn_s_setprio(0);
  };

  short8 a0[8], a1[8];
  const int NT = DIM_F / 64;   // 16
  loadB(0);
  ldA(0, a0);
  writeB(0);
  __syncthreads();
  #pragma unroll 1
  for (int it = 0; it < NT / 2; it++) {
    const int kt1 = it * 2 + 1;
    loadB(kt1 * 64);
    ldA(kt1 * 64, a1);
    compute(0, a0);
    writeB(1);
    __syncthreads();
    if (kt1 + 1 < NT) {
      loadB((kt1 + 1) * 64);
      ldA((kt1 + 1) * 64, a0);
    }
    compute(1, a1);
    if (kt1 + 1 < NT) writeB(0);
    __syncthreads();
  }

  #pragma unroll
  for (int mi = 0; mi < 4; mi++)
    #pragma unroll
    for (int ni = 0; ni < 4; ni++) {
      int col = col0 + wn * 64 + ni * 16 + (lane & 15);
      int rbase = row0 + wm * 64 + mi * 16 + (lane >> 4) * 4;
      #pragma unroll
      for (int j = 0; j < 4; j++)
        out[(size_t)(rbase + j) * DIM_H + col] = acc[mi][ni][j];
    }
}

extern "C" void kernel_launch(void* const* d_in, const int* in_sizes, int n_in,
                              void* d_out, int out_size, void* d_ws, size_t ws_size,
                              hipStream_t stream) {
  (void)in_sizes; (void)n_in; (void)out_size; (void)ws_size;
  const float* x  = (const float*)d_in[0];
  // d_in[1] = tokens_per_expert: equal-count setup (C=512 each), static dispatch.
  const float* wg = (const float*)d_in[2];
  const float* wu = (const float*)d_in[3];
  const float* wd = (const float*)d_in[4];
  unsigned short* h   = (unsigned short*)d_ws;                        // 64 MiB
  unsigned short* xbf = (unsigned short*)((char*)d_ws + (size_t)NTOK * DIM_F * 2); // 64 MiB
  float* out = (float*)d_out;

  cvt_kernel<<<dim3((NTOK * DIM_H) / (256 * 8)), dim3(256), 0, stream>>>(x, xbf);
  gateup_kernel_v5<<<dim3(1024), dim3(512), 0, stream>>>(xbf, wg, wu, h);
  down_kernel_v5<<<dim3(1024), dim3(512), 0, stream>>>(h, wd, out);
}

// Round 8
// 403.013 us; speedup vs baseline: 3.1041x; 3.1041x over previous
//
#include <hip/hip_runtime.h>
#include <stdint.h>

// SequentialMLP (grouped MoE LLaMA-MLP), MI355X gfx950.
// E=64 experts x C=512 tokens, H=F=1024, f32 in/out, bf16 MFMA compute.
// R8: revert R7's A-direct (L2-thrash: FETCH 295MB->1.29GB, 3x slower).
//     Structure = R5 (best): A via global_load_lds (pre-swizzled src, linear
//     dest), 256m x 128n fat blocks, 512thr/8 waves, 16x16x32 MFMA, dbuf A+B,
//     1 barrier/K-tile, counted vmcnt, setprio, XCD swizzle.
//     + R6's one good piece: vectorized B gather (4x dwordx4 + reg transpose,
//     8 VMEM vs 32 scalar per thread/tile; writes audited <=2-way conflict).

#define NUM_E 64
#define DIM_H 1024
#define DIM_F 1024
#define CAP   512
#define NTOK  32768

typedef short short8 __attribute__((ext_vector_type(8)));
typedef float f32x4 __attribute__((ext_vector_type(4)));

#define VMCNT(n)  asm volatile("s_waitcnt vmcnt(" #n ")" ::: "memory")
#define LGKMCNT0  asm volatile("s_waitcnt lgkmcnt(0)" ::: "memory")
#define SBAR      __builtin_amdgcn_s_barrier()
#define SCHED0    __builtin_amdgcn_sched_barrier(0)

__device__ __forceinline__ uint32_t cvtpk(float lo, float hi) {
  uint32_t r;
  asm("v_cvt_pk_bf16_f32 %0, %1, %2" : "=v"(r) : "v"(lo), "v"(hi));
  return r;
}
__device__ __forceinline__ unsigned short f2bf(float a) {
  uint32_t ua = __builtin_bit_cast(uint32_t, a);
  ua += 0x7FFFu + ((ua >> 16) & 1u);
  return (unsigned short)(ua >> 16);
}
__device__ __forceinline__ void gload_lds16(const void* g, void* l) {
  __builtin_amdgcn_global_load_lds((const __attribute__((address_space(1))) uint32_t*)g,
                                   (__attribute__((address_space(3))) uint32_t*)l, 16, 0, 0);
}

// ---------------- Kernel 0: x f32 -> bf16 ----------------
__global__ __launch_bounds__(256) void cvt_kernel(const float* __restrict__ x,
                                                  unsigned short* __restrict__ xbf) {
  size_t i = ((size_t)blockIdx.x * 256 + threadIdx.x) * 8;
  f32x4 a = *reinterpret_cast<const f32x4*>(x + i);
  f32x4 b = *reinterpret_cast<const f32x4*>(x + i + 4);
  int4 o = make_int4((int)cvtpk(a[0], a[1]), (int)cvtpk(a[2], a[3]),
                     (int)cvtpk(b[0], b[1]), (int)cvtpk(b[2], b[3]));
  *reinterpret_cast<int4*>(xbf + i) = o;
}

// ------ Kernel 1: h = silu(x Wg)*(x Wu).  256m x (128g+128u), BK=64 ------
// 512 thr / 8 waves (4m x 2n), wave tile 64x64 per matrix, 16x16x32 MFMA.
// Grid 64e x 2mb x 8nb = 1024. LDS 128KB: A 2x32KB @0; B 2x{Bg 16KB,Bu 16KB} @65536.
__global__ __launch_bounds__(512, 2) void gateup_kernel_v6(
    const unsigned short* __restrict__ xbf, const float* __restrict__ wg,
    const float* __restrict__ wu, unsigned short* __restrict__ hout)
{
  __shared__ unsigned char smem[131072];
  const int t = threadIdx.x;
  int bid = blockIdx.x;
  bid = (bid & 7) * 128 + (bid >> 3);          // XCD-bijective (1024 = 8*128)
  const int e = bid >> 4, rr = bid & 15, mb = rr >> 3, nb = rr & 7;
  const int row0 = e * CAP + mb * 256;
  const int col0 = nb * 128;
  const unsigned short* Ag = xbf + (size_t)row0 * DIM_H;
  const float* Bgg = wg + (size_t)e * (DIM_H * DIM_F) + col0;
  const float* Bug = wu + (size_t)e * (DIM_H * DIM_F) + col0;

  const int lane = t & 63, wid = t >> 6;
  const int wm = wid >> 1, wn = wid & 1;       // wave tile 64m x 64n (per matrix)

  f32x4 accg[4][4], accu[4][4];
  #pragma unroll
  for (int i = 0; i < 4; i++)
    #pragma unroll
    for (int j = 0; j < 4; j++) {
      accg[i][j] = f32x4{0.f, 0.f, 0.f, 0.f};
      accu[i][j] = f32x4{0.f, 0.f, 0.f, 0.f};
    }

  // B staging: thread covers 4k x 4n f32 per matrix (dwordx4 x4, reg transpose)
  const int kg = t & 15, ng = t >> 4;          // k = kg*4+i, n = ng*4+j
  f32x4 vg[4], vu[4];

  auto loadB = [&](int k0) {
    #pragma unroll
    for (int i = 0; i < 4; i++) {
      size_t off = (size_t)(k0 + kg * 4 + i) * DIM_F + ng * 4;
      vg[i] = *reinterpret_cast<const f32x4*>(Bgg + off);
      vu[i] = *reinterpret_cast<const f32x4*>(Bug + off);
    }
  };
  auto writeB = [&](int b) {
    const int Bb = 65536 + b * 32768;
    #pragma unroll
    for (int j = 0; j < 4; j++) {
      int n = ng * 4 + j;
      int off = Bb + n * 128 + ((kg * 8) ^ ((n & 7) << 4));
      *reinterpret_cast<uint2*>(&smem[off]) =
          make_uint2(cvtpk(vg[0][j], vg[1][j]), cvtpk(vg[2][j], vg[3][j]));
      *reinterpret_cast<uint2*>(&smem[off + 16384]) =
          make_uint2(cvtpk(vu[0][j], vu[1][j]), cvtpk(vu[2][j], vu[3][j]));
    }
  };
  // A tile 256x64 bf16 = 32KB via global_load_lds; linear dest, pre-swizzled src.
  auto loadA = [&](int k0, int buf) {
    #pragma unroll
    for (int j = 0; j < 4; j++) {
      int lin = (j * 512 + t) * 16;
      int r = lin >> 7;             // 128B per row
      int q = (lin >> 4) & 7;
      const void* src = (const unsigned char*)Ag + (size_t)r * 2048 + k0 * 2 + ((q ^ (r & 7)) * 16);
      gload_lds16(src, &smem[buf * 32768 + lin]);
    }
  };
  auto compute = [&](int kt) {
    const int Ab = (kt & 1) * 32768;
    const int Bb = 65536 + (kt & 1) * 32768;
    __builtin_amdgcn_s_setprio(1);
    #pragma unroll
    for (int kk = 0; kk < 2; kk++) {
      short8 a[4], bgf[4], buf_[4];
      #pragma unroll
      for (int mi = 0; mi < 4; mi++) {
        int r = wm * 64 + mi * 16 + (lane & 15);
        a[mi] = *reinterpret_cast<const short8*>(
            &smem[Ab + r * 128 + ((kk * 64 + (lane >> 4) * 16) ^ ((r & 7) << 4))]);
      }
      #pragma unroll
      for (int ni = 0; ni < 4; ni++) {
        int n = wn * 64 + ni * 16 + (lane & 15);
        int off = Bb + n * 128 + ((kk * 64 + (lane >> 4) * 16) ^ ((n & 7) << 4));
        bgf[ni]  = *reinterpret_cast<const short8*>(&smem[off]);
        buf_[ni] = *reinterpret_cast<const short8*>(&smem[off + 16384]);
      }
      #pragma unroll
      for (int mi = 0; mi < 4; mi++)
        #pragma unroll
        for (int ni = 0; ni < 4; ni++) {
          accg[mi][ni] = __builtin_amdgcn_mfma_f32_16x16x32_bf16(a[mi], bgf[ni],  accg[mi][ni], 0, 0, 0);
          accu[mi][ni] = __builtin_amdgcn_mfma_f32_16x16x32_bf16(a[mi], buf_[ni], accu[mi][ni], 0, 0, 0);
        }
    }
    __builtin_amdgcn_s_setprio(0);
  };

  const int NT = DIM_H / 64;   // 16
  loadB(0);
  loadA(0, 0);
  VMCNT(4); SCHED0;            // 8 B loads done; 4 A gloads in flight
  writeB(0);
  LGKMCNT0; VMCNT(0); SCHED0;
  SBAR;
  for (int kt = 0; kt < NT; kt++) {
    if (kt + 1 < NT) {
      loadB((kt + 1) * 64);
      loadA((kt + 1) * 64, (kt + 1) & 1);
      SCHED0;
    }
    compute(kt);
    if (kt + 1 < NT) {
      VMCNT(4); SCHED0;        // B(t+1) done; A(t+1) gloads in flight
      writeB((kt + 1) & 1);
      LGKMCNT0; VMCNT(0); SCHED0;
      SBAR;
    }
  }

  // epilogue: silu(g)*u -> bf16. C/D: col=lane&15, row=(lane>>4)*4+j.
  #pragma unroll
  for (int mi = 0; mi < 4; mi++)
    #pragma unroll
    for (int ni = 0; ni < 4; ni++) {
      int col = col0 + wn * 64 + ni * 16 + (lane & 15);
      int rbase = row0 + wm * 64 + mi * 16 + (lane >> 4) * 4;
      #pragma unroll
      for (int j = 0; j < 4; j++) {
        float g = accg[mi][ni][j], u = accu[mi][ni][j];
        float hv = (g / (1.f + __expf(-g))) * u;
        hout[(size_t)(rbase + j) * DIM_F + col] = f2bf(hv);
      }
    }
}

// ---------------- Kernel 2: out = h Wd, f32 out.  256m x 128n ----------------
// 512 thr / 8 waves (4m x 2n), wave 64x64, 16x16x32 MFMA. Grid 1024.
// LDS 96KB: A 2x32KB @0; Bd^T 2x16KB @65536.
__global__ __launch_bounds__(512, 2) void down_kernel_v6(
    const unsigned short* __restrict__ hin, const float* __restrict__ wd,
    float* __restrict__ out)
{
  __shared__ unsigned char smem[98304];
  const int t = threadIdx.x;
  int bid = blockIdx.x;
  bid = (bid & 7) * 128 + (bid >> 3);          // XCD-bijective (1024 = 8*128)
  const int e = bid >> 4, rr = bid & 15, mb = rr >> 3, nb = rr & 7;
  const int row0 = e * CAP + mb * 256;
  const int col0 = nb * 128;
  const unsigned short* Ag = hin + (size_t)row0 * DIM_F;
  const float* Bdg = wd + (size_t)e * (DIM_F * DIM_H) + col0;

  const int lane = t & 63, wid = t >> 6;
  const int wm = wid >> 1, wn = wid & 1;

  f32x4 acc[4][4];
  #pragma unroll
  for (int i = 0; i < 4; i++)
    #pragma unroll
    for (int j = 0; j < 4; j++) acc[i][j] = f32x4{0.f, 0.f, 0.f, 0.f};

  const int kg = t & 15, ng = t >> 4;
  f32x4 vb[4];

  auto loadB = [&](int k0) {
    #pragma unroll
    for (int i = 0; i < 4; i++)
      vb[i] = *reinterpret_cast<const f32x4*>(Bdg + (size_t)(k0 + kg * 4 + i) * DIM_H + ng * 4);
  };
  auto writeB = [&](int b) {
    const int Bb = 65536 + b * 16384;
    #pragma unroll
    for (int j = 0; j < 4; j++) {
      int n = ng * 4 + j;
      int off = Bb + n * 128 + ((kg * 8) ^ ((n & 7) << 4));
      *reinterpret_cast<uint2*>(&smem[off]) =
          make_uint2(cvtpk(vb[0][j], vb[1][j]), cvtpk(vb[2][j], vb[3][j]));
    }
  };
  auto loadA = [&](int k0, int buf) {
    #pragma unroll
    for (int j = 0; j < 4; j++) {
      int lin = (j * 512 + t) * 16;
      int r = lin >> 7;
      int q = (lin >> 4) & 7;
      const void* src = (const unsigned char*)Ag + (size_t)r * 2048 + k0 * 2 + ((q ^ (r & 7)) * 16);
      gload_lds16(src, &smem[buf * 32768 + lin]);
    }
  };
  auto compute = [&](int kt) {
    const int Ab = (kt & 1) * 32768;
    const int Bb = 65536 + (kt & 1) * 16384;
    __builtin_amdgcn_s_setprio(1);
    #pragma unroll
    for (int kk = 0; kk < 2; kk++) {
      short8 a[4], b[4];
      #pragma unroll
      for (int mi = 0; mi < 4; mi++) {
        int r = wm * 64 + mi * 16 + (lane & 15);
        a[mi] = *reinterpret_cast<const short8*>(
            &smem[Ab + r * 128 + ((kk * 64 + (lane >> 4) * 16) ^ ((r & 7) << 4))]);
      }
      #pragma unroll
      for (int ni = 0; ni < 4; ni++) {
        int n = wn * 64 + ni * 16 + (lane & 15);
        b[ni] = *reinterpret_cast<const short8*>(
            &smem[Bb + n * 128 + ((kk * 64 + (lane >> 4) * 16) ^ ((n & 7) << 4))]);
      }
      #pragma unroll
      for (int mi = 0; mi < 4; mi++)
        #pragma unroll
        for (int ni = 0; ni < 4; ni++)
          acc[mi][ni] = __builtin_amdgcn_mfma_f32_16x16x32_bf16(a[mi], b[ni], acc[mi][ni], 0, 0, 0);
    }
    __builtin_amdgcn_s_setprio(0);
  };

  const int NT = DIM_F / 64;   // 16
  loadB(0);
  loadA(0, 0);
  VMCNT(4); SCHED0;            // 4 B loads done; 4 A gloads in flight
  writeB(0);
  LGKMCNT0; VMCNT(0); SCHED0;
  SBAR;
  for (int kt = 0; kt < NT; kt++) {
    if (kt + 1 < NT) {
      loadB((kt + 1) * 64);
      loadA((kt + 1) * 64, (kt + 1) & 1);
      SCHED0;
    }
    compute(kt);
    if (kt + 1 < NT) {
      VMCNT(4); SCHED0;
      writeB((kt + 1) & 1);
      LGKMCNT0; VMCNT(0); SCHED0;
      SBAR;
    }
  }

  #pragma unroll
  for (int mi = 0; mi < 4; mi++)
    #pragma unroll
    for (int ni = 0; ni < 4; ni++) {
      int col = col0 + wn * 64 + ni * 16 + (lane & 15);
      int rbase = row0 + wm * 64 + mi * 16 + (lane >> 4) * 4;
      #pragma unroll
      for (int j = 0; j < 4; j++)
        out[(size_t)(rbase + j) * DIM_H + col] = acc[mi][ni][j];
    }
}

extern "C" void kernel_launch(void* const* d_in, const int* in_sizes, int n_in,
                              void* d_out, int out_size, void* d_ws, size_t ws_size,
                              hipStream_t stream) {
  (void)in_sizes; (void)n_in; (void)out_size; (void)ws_size;
  const float* x  = (const float*)d_in[0];
  // d_in[1] = tokens_per_expert: equal-count setup (C=512 each), static dispatch.
  const float* wg = (const float*)d_in[2];
  const float* wu = (const float*)d_in[3];
  const float* wd = (const float*)d_in[4];
  unsigned short* h   = (unsigned short*)d_ws;                        // 64 MiB
  unsigned short* xbf = (unsigned short*)((char*)d_ws + (size_t)NTOK * DIM_F * 2); // 64 MiB
  float* out = (float*)d_out;

  cvt_kernel<<<dim3((NTOK * DIM_H) / (256 * 8)), dim3(256), 0, stream>>>(x, xbf);
  gateup_kernel_v6<<<dim3(1024), dim3(512), 0, stream>>>(xbf, wg, wu, h);
  down_kernel_v6<<<dim3(1024), dim3(512), 0, stream>>>(h, wd, out);
}